// Round 25
// baseline (258.837 us; speedup 1.0000x reference)
//
#include <hip/hip_runtime.h>

// GCN 2-layer. Round-24: 247us (-22 from 16-lane gather split -- gathers
// confirmed latency-bound). This round: extend to 32 lanes/node (4 edge-
// quarters x 8 f-lanes, j+=4 => ~8 serial iters), combine via shfl_xor(8)
// + shfl_xor(16). Class math on q==0 lanes. Everything else unchanged.

#define NF 512
#define NH 16
#define NRANGE 32
#define NS2 32
#define RS 3125           // nodes per range = 100000/32
#define EB 1024           // edges per bin block
#define GROWS 128         // gemm rows per block
#define GK 16             // gemm k-chunk (double-buffered)
#define XST 20            // xs row stride in floats (80B: aligned + spread)

__device__ __forceinline__ unsigned short f2bf(float f) {
    unsigned u = __float_as_uint(f);
    return (unsigned short)((u + 0x7fff + ((u >> 16) & 1)) >> 16);   // RNE
}
__device__ __forceinline__ float bf2f(unsigned b) {
    return __uint_as_float(b << 16);
}

__global__ __launch_bounds__(256) void k_bincount(const int* __restrict__ dst,
                                                  int* __restrict__ bktcnt,
                                                  int E, int nblk) {
    __shared__ int cnt[NRANGE];
    if (threadIdx.x < NRANGE) cnt[threadIdx.x] = 0;
    __syncthreads();
    int b0 = blockIdx.x * EB;
#pragma unroll
    for (int j = 0; j < 4; ++j) {
        int e = b0 + j * 256 + threadIdx.x;
        if (e < E) atomicAdd(&cnt[dst[e] / RS], 1);
    }
    __syncthreads();
    if (threadIdx.x < NRANGE)
        bktcnt[threadIdx.x * nblk + blockIdx.x] = cnt[threadIdx.x];
}

// exclusive scan (verified rounds 6-24); safe with out==in
__global__ __launch_bounds__(256) void k_scan_block(const int* __restrict__ in,
                                                    int* __restrict__ outp,
                                                    int* __restrict__ bsum, int n) {
    __shared__ int sh[256];
    int t = threadIdx.x, g = blockIdx.x * 256 + t;
    int v = (g < n) ? in[g] : 0;
    sh[t] = v; __syncthreads();
    for (int off = 1; off < 256; off <<= 1) {
        int a = (t >= off) ? sh[t - off] : 0;
        __syncthreads();
        sh[t] += a;
        __syncthreads();
    }
    if (g < n) outp[g] = sh[t] - v;
    if (t == 255) bsum[blockIdx.x] = sh[255];
}

// fused: per-node degree+weight reduction (packed), dinv write, block scan
__global__ __launch_bounds__(256) void k_sumscan(const unsigned* __restrict__ partials,
                                                 int* __restrict__ rowptr,
                                                 int* __restrict__ bsum,
                                                 float* __restrict__ dinv, int n) {
    __shared__ int sh[256];
    int t = threadIdx.x, g = blockIdx.x * 256 + t;
    int v = 0;
    if (g < n) {
        int r = g / RS, b = g - r * RS;
        const unsigned* p = partials + (size_t)(r * NS2) * RS + b;
        unsigned wq = 0;
#pragma unroll
        for (int s = 0; s < NS2; ++s) {
            unsigned pk = p[s * RS];
            v += (int)(pk >> 25);
            wq += pk & 0x1ffffffu;
        }
        dinv[g] = rsqrtf(1.0f + (float)wq * (1.0f / 1024.0f));
    }
    sh[t] = v; __syncthreads();
    for (int off = 1; off < 256; off <<= 1) {
        int a = (t >= off) ? sh[t - off] : 0;
        __syncthreads();
        sh[t] += a;
        __syncthreads();
    }
    if (g < n) rowptr[g] = sh[t] - v;     // block-local; bsum added by consumers
    if (t == 255) bsum[blockIdx.x] = sh[255];
}

__global__ __launch_bounds__(512) void k_scan_tops(int* __restrict__ bsum,
                                                   int* __restrict__ outp,
                                                   int nb, int n) {
    __shared__ int sh[512];
    int t = threadIdx.x;
    int v = (t < nb) ? bsum[t] : 0;
    sh[t] = v; __syncthreads();
    for (int off = 1; off < 512; off <<= 1) {
        int a = (t >= off) ? sh[t - off] : 0;
        __syncthreads();
        sh[t] += a;
        __syncthreads();
    }
    if (t < nb) bsum[t] = sh[t] - v;
    if (t == 511) outp[n] = sh[511];      // absolute total (E)
}

// write each edge once into its bucket; bsum2 offset applied inline
__global__ __launch_bounds__(256) void k_binfill(const int* __restrict__ src,
                                                 const int* __restrict__ dst,
                                                 const float* __restrict__ ew,
                                                 const int* __restrict__ bktcnt,
                                                 const int* __restrict__ bsum2,
                                                 int2* __restrict__ bin,
                                                 int E, int nblk) {
    __shared__ int base[NRANGE];
    if (threadIdx.x < NRANGE) {
        int idx = threadIdx.x * nblk + blockIdx.x;
        base[threadIdx.x] = bktcnt[idx] + bsum2[idx >> 8];
    }
    __syncthreads();
    int b0 = blockIdx.x * EB;
#pragma unroll
    for (int j = 0; j < 4; ++j) {
        int e = b0 + j * 256 + threadIdx.x;
        if (e < E) {
            int d = dst[e];
            int r = d / RS;
            int pos = atomicAdd(&base[r], 1);          // LDS only
            bin[pos] = make_int2((src[e] << 12) | (d - r * RS),
                                 __float_as_int(ew[e]));
        }
    }
}

__device__ __forceinline__ int bkt_start(const int* bktcnt, const int* bsum2,
                                         int r, int nblk, int E) {
    if (r >= NRANGE) return E;
    int idx = r * nblk;
    return bktcnt[idx] + bsum2[idx >> 8];
}

// per-(range, slice) packed LDS histogram: (count<<25) | sum(round(ew*1024))
__global__ __launch_bounds__(256) void k_hist2(const int2* __restrict__ bin,
                                               const int* __restrict__ bktcnt,
                                               const int* __restrict__ bsum2,
                                               unsigned* __restrict__ partials,
                                               int E, int nblk) {
    __shared__ unsigned hist[RS];
    int r = blockIdx.x >> 5, s = blockIdx.x & (NS2 - 1);
    for (int t = threadIdx.x; t < RS; t += 256) hist[t] = 0;
    __syncthreads();
    int b0 = bkt_start(bktcnt, bsum2, r, nblk, E);
    int b1 = bkt_start(bktcnt, bsum2, r + 1, nblk, E);
    int len = b1 - b0, ss = (len + NS2 - 1) / NS2;
    int cs = b0 + s * ss, ce = min(cs + ss, b1);
    for (int j = cs + threadIdx.x; j < ce; j += 256) {
        int2 p2 = bin[j];
        unsigned wq = (unsigned)(__int_as_float(p2.y) * 1024.0f + 0.5f);
        atomicAdd(&hist[p2.x & 4095], (1u << 25) | wq);
    }
    __syncthreads();
    unsigned* pp = partials + (size_t)(r * NS2 + s) * RS;
    for (int t = threadIdx.x; t < RS; t += 256) pp[t] = hist[t];
}

// per-slice packed counts -> exact ABSOLUTE slot starts (bsum folded in)
__global__ __launch_bounds__(256) void k_slicecur(unsigned* __restrict__ partials,
                                                  const int* __restrict__ rowptr,
                                                  const int* __restrict__ bsum, int n) {
    int d = blockIdx.x * 256 + threadIdx.x;
    if (d >= n) return;
    int r = d / RS, b = d - r * RS;
    unsigned* p = partials + (size_t)(r * NS2) * RS + b;
    int run = rowptr[d] + bsum[d >> 8];
#pragma unroll
    for (int s = 0; s < NS2; ++s) {
        int c = (int)(p[s * RS] >> 25);
        p[s * RS] = (unsigned)run;
        run += c;
    }
}

// place edges: csr = (src<<15) | fixed15(dinv[s]*ew*dinv[d])
__global__ __launch_bounds__(256) void k_fill3(const int2* __restrict__ bin,
                                               const int* __restrict__ bktcnt,
                                               const int* __restrict__ bsum2,
                                               const unsigned* __restrict__ partials,
                                               const float* __restrict__ dinv,
                                               unsigned* __restrict__ csr,
                                               int E, int nblk) {
    __shared__ int cur[RS];
    __shared__ float dv[RS];
    int r = blockIdx.x >> 5, s = blockIdx.x & (NS2 - 1);
    const unsigned* cp = partials + (size_t)(r * NS2 + s) * RS;
    for (int t = threadIdx.x; t < RS; t += 256) {
        cur[t] = (int)cp[t];
        dv[t] = dinv[r * RS + t];
    }
    __syncthreads();
    int b0 = bkt_start(bktcnt, bsum2, r, nblk, E);
    int b1 = bkt_start(bktcnt, bsum2, r + 1, nblk, E);
    int len = b1 - b0, ss = (len + NS2 - 1) / NS2;
    int cs = b0 + s * ss, ce = min(cs + ss, b1);
    for (int j = cs + threadIdx.x; j < ce; j += 256) {
        int2 p2 = bin[j];
        int dl = p2.x & 4095;
        int sn = p2.x >> 12;
        float nrm = dinv[sn] * __int_as_float(p2.y) * dv[dl];
        unsigned w15 = (unsigned)(nrm * 32767.0f + 0.5f);
        int pos = atomicAdd(&cur[dl], 1);             // LDS only
        csr[pos] = ((unsigned)sn << 15) | w15;
    }
}

// h = x @ W1: dbuf fp32 xs (XST=20) + bf16 W1 (16KB). 36KB -> 4 blocks/CU.
__global__ __launch_bounds__(256) void k_gemm1(const float* __restrict__ x,
                                               const float* __restrict__ w1,
                                               unsigned short* __restrict__ h, int n) {
    __shared__ unsigned wtb[NF * NH / 2];  // 16KB bf16 pairs [k4][f][kk/2]
    __shared__ float xs[2][GROWS * XST];   // 2 x 10KB
    for (int idx = threadIdx.x; idx < NF * NH / 2; idx += 256) {
        int k4 = idx >> 5, rem = idx & 31;
        int f = rem >> 1, kk = (rem & 1) * 2;
        float v0 = w1[(k4 * 4 + kk) * NH + f];
        float v1 = w1[(k4 * 4 + kk + 1) * NH + f];
        wtb[idx] = (unsigned)f2bf(v0) | ((unsigned)f2bf(v1) << 16);
    }
    int rq = threadIdx.x >> 2;             // 0..63
    int fq = threadIdx.x & 3;              // 0..3
    int base = blockIdx.x * GROWS;
    float4 stage[2];
#define LOAD_CHUNK(kc)                                                        \
    _Pragma("unroll")                                                         \
    for (int li = 0; li < 2; ++li) {                                          \
        int idx = li * 256 + threadIdx.x;                                     \
        int row = idx >> 2, c4 = idx & 3;                                     \
        int rg = base + row; if (rg > n - 1) rg = n - 1;                      \
        stage[li] = *(const float4*)(x + (size_t)rg * NF + (kc) * GK + c4 * 4);\
    }
#define WRITE_CHUNK(b)                                                        \
    _Pragma("unroll")                                                         \
    for (int li = 0; li < 2; ++li) {                                          \
        int idx = li * 256 + threadIdx.x;                                     \
        int row = idx >> 2, c4 = idx & 3;                                     \
        float* p = &xs[b][row * XST + c4 * 4];                                \
        p[0] = stage[li].x; p[1] = stage[li].y;                               \
        p[2] = stage[li].z; p[3] = stage[li].w;                               \
    }
    float acc[2][4] = {{0.f}};
    LOAD_CHUNK(0)
    WRITE_CHUNK(0)
    __syncthreads();                       // also covers wtb
    for (int kc = 0; kc < NF / GK; ++kc) {
        if (kc + 1 < NF / GK) { LOAD_CHUNK(kc + 1) }   // in flight over compute
        int b = kc & 1;
#pragma unroll
        for (int k4c = 0; k4c < GK / 4; ++k4c) {
            int k4 = kc * (GK / 4) + k4c;
            float4 wf[4];
#pragma unroll
            for (int c = 0; c < 4; ++c) {
                uint2 u = *(const uint2*)&wtb[k4 * 32 + (fq * 4 + c) * 2];
                wf[c].x = __uint_as_float(u.x << 16);
                wf[c].y = __uint_as_float(u.x & 0xffff0000u);
                wf[c].z = __uint_as_float(u.y << 16);
                wf[c].w = __uint_as_float(u.y & 0xffff0000u);
            }
#pragma unroll
            for (int i = 0; i < 2; ++i) {
                int row = rq * 2 + i;
                float4 xv = *(const float4*)&xs[b][row * XST + k4c * 4];
#pragma unroll
                for (int c = 0; c < 4; ++c) {
                    acc[i][c] = fmaf(xv.x, wf[c].x, acc[i][c]);
                    acc[i][c] = fmaf(xv.y, wf[c].y, acc[i][c]);
                    acc[i][c] = fmaf(xv.z, wf[c].z, acc[i][c]);
                    acc[i][c] = fmaf(xv.w, wf[c].w, acc[i][c]);
                }
            }
        }
        if (kc + 1 < NF / GK) {
            __syncthreads();
            WRITE_CHUNK((kc + 1) & 1)      // vmcnt drain behind compute
            __syncthreads();
        }
    }
#pragma unroll
    for (int i = 0; i < 2; ++i) {
        int r = base + rq * 2 + i;
        if (r < n) {
            ushort4 o;
            o.x = f2bf(acc[i][0]); o.y = f2bf(acc[i][1]);
            o.z = f2bf(acc[i][2]); o.w = f2bf(acc[i][3]);
            *(ushort4*)(h + (size_t)r * NH + fq * 4) = o;
        }
    }
#undef LOAD_CHUNK
#undef WRITE_CHUNK
}

// layer-1 gather + bias/relu; 32 lanes/node = 4 edge-quarters x 8 f-lanes
__global__ __launch_bounds__(256) void k_gather_relu(const unsigned short* __restrict__ in,
                                                     const float* __restrict__ dinv,
                                                     const int* __restrict__ rowptr,
                                                     const int* __restrict__ bsum,
                                                     const unsigned* __restrict__ csr,
                                                     const float* __restrict__ b1,
                                                     unsigned short* __restrict__ out, int n) {
    int tid = blockIdx.x * 256 + threadIdx.x;
    int d = tid >> 5, l = tid & 7, q = (tid >> 3) & 3;
    if (d >= n) return;
    float di = dinv[d];
    float a0 = 0.0f, a1 = 0.0f;
    if (q == 0) {
        unsigned self = *(const unsigned*)(in + (size_t)d * NH + 2 * l);
        a0 = bf2f(self & 0xffffu) * di * di;
        a1 = bf2f(self >> 16) * di * di;
    }
    int e0 = rowptr[d] + bsum[d >> 8];
    int e1 = (d + 1 < n) ? rowptr[d + 1] + bsum[(d + 1) >> 8] : rowptr[n];
#pragma unroll 2
    for (int j = e0 + q; j < e1; j += 4) {
        unsigned e = csr[j];
        float nrm = (float)(e & 32767u) * (1.0f / 32767.0f);
        unsigned pr = *(const unsigned*)(in + (size_t)(e >> 15) * NH + 2 * l);
        a0 = fmaf(bf2f(pr & 0xffffu), nrm, a0);
        a1 = fmaf(bf2f(pr >> 16), nrm, a1);
    }
    a0 += __shfl_xor(a0, 8, 32);           // combine quarters
    a1 += __shfl_xor(a1, 8, 32);
    a0 += __shfl_xor(a0, 16, 32);
    a1 += __shfl_xor(a1, 16, 32);
    if (q == 0) {
        a0 = fmaxf(a0 + b1[2 * l], 0.0f);
        a1 = fmaxf(a1 + b1[2 * l + 1], 0.0f);
        unsigned pk = (unsigned)f2bf(a0) | ((unsigned)f2bf(a1) << 16);
        *(unsigned*)(out + (size_t)d * NH + 2 * l) = pk;
    }
}

// layer-2 gather + W2 + b2 + log_softmax; 32 lanes/node, quarters combined,
// class math on q==0 lanes (8 lanes x 5 classes).
__global__ __launch_bounds__(256) void k_gather_out(const unsigned short* __restrict__ in,
                                                    const float* __restrict__ dinv,
                                                    const int* __restrict__ rowptr,
                                                    const int* __restrict__ bsum,
                                                    const unsigned* __restrict__ csr,
                                                    const float* __restrict__ w2,
                                                    const float* __restrict__ b2,
                                                    float* __restrict__ out, int n) {
    __shared__ float w2s[NH * 40];
    __shared__ float b2s[40];
    for (int t = threadIdx.x; t < NH * 40; t += 256) w2s[t] = w2[t];
    if (threadIdx.x < 40) b2s[threadIdx.x] = b2[threadIdx.x];
    __syncthreads();
    int tid = blockIdx.x * 256 + threadIdx.x;
    int d = tid >> 5, l = tid & 7, q = (tid >> 3) & 3;
    if (d >= n) return;
    float di = dinv[d];
    float a0 = 0.0f, a1 = 0.0f;
    if (q == 0) {
        unsigned self = *(const unsigned*)(in + (size_t)d * NH + 2 * l);
        a0 = bf2f(self & 0xffffu) * di * di;
        a1 = bf2f(self >> 16) * di * di;
    }
    int e0 = rowptr[d] + bsum[d >> 8];
    int e1 = (d + 1 < n) ? rowptr[d + 1] + bsum[(d + 1) >> 8] : rowptr[n];
#pragma unroll 2
    for (int j = e0 + q; j < e1; j += 4) {
        unsigned e = csr[j];
        float nrm = (float)(e & 32767u) * (1.0f / 32767.0f);
        unsigned pr = *(const unsigned*)(in + (size_t)(e >> 15) * NH + 2 * l);
        a0 = fmaf(bf2f(pr & 0xffffu), nrm, a0);
        a1 = fmaf(bf2f(pr >> 16), nrm, a1);
    }
    a0 += __shfl_xor(a0, 8, 32);           // combine quarters
    a1 += __shfl_xor(a1, 8, 32);
    a0 += __shfl_xor(a0, 16, 32);
    a1 += __shfl_xor(a1, 16, 32);
    // all 32 lanes hold full sums; exchange 16 features within the group
    float v[NH];
#pragma unroll
    for (int m = 0; m < 8; ++m) {
        v[2 * m] = __shfl(a0, m, 32);
        v[2 * m + 1] = __shfl(a1, m, 32);
    }
    float z[5];
#pragma unroll
    for (int j5 = 0; j5 < 5; ++j5) {
        int c = l * 5 + j5;
        float a = b2s[c];
#pragma unroll
        for (int ff = 0; ff < NH; ++ff) a = fmaf(v[ff], w2s[ff * 40 + c], a);
        z[j5] = a;
    }
    float mx = z[0];
#pragma unroll
    for (int j5 = 1; j5 < 5; ++j5) mx = fmaxf(mx, z[j5]);
#pragma unroll
    for (int off = 4; off; off >>= 1) mx = fmaxf(mx, __shfl_xor(mx, off, 8));
    float sum = 0.0f;
#pragma unroll
    for (int j5 = 0; j5 < 5; ++j5) sum += expf(z[j5] - mx);
#pragma unroll
    for (int off = 4; off; off >>= 1) sum += __shfl_xor(sum, off, 8);
    float ls = mx + logf(sum);
    if (q == 0) {
        float* op = out + (size_t)d * 40 + l * 5;
#pragma unroll
        for (int j5 = 0; j5 < 5; ++j5) op[j5] = z[j5] - ls;
    }
}

extern "C" void kernel_launch(void* const* d_in, const int* in_sizes, int n_in,
                              void* d_out, int out_size, void* d_ws, size_t ws_size,
                              hipStream_t stream) {
    const float* x  = (const float*)d_in[0];
    const int*   ei = (const int*)d_in[1];
    const float* ew = (const float*)d_in[2];
    const float* w1 = (const float*)d_in[3];
    const float* b1 = (const float*)d_in[4];
    const float* w2 = (const float*)d_in[5];
    const float* b2 = (const float*)d_in[6];
    float* out = (float*)d_out;

    int n = in_sizes[0] / NF;      // 100000 (= NRANGE*RS)
    int E = in_sizes[2];           // 3200000
    const int* src = ei;
    const int* dst = ei + E;

    float*          ws       = (float*)d_ws;
    float*          dinv     = ws;                        // n
    int*            bsum     = (int*)(ws + 200000);       // 1024
    int*            rowptr   = (int*)(ws + 201024);       // n+1
    int*            bsum2    = (int*)(ws + 301056);       // 1024
    int*            bktcnt   = (int*)(ws + 302080);       // 100032
    unsigned*       partials = (unsigned*)(ws + 402112);  // 3.2M packed
    unsigned*       csr      = (unsigned*)(ws + 6802112); // E
    int2*           bin      = (int2*)(ws + 10002112);    // 2E, dead after fill3
    unsigned short* h        = (unsigned short*)(ws + 10002112);  // overlays bin
    unsigned short* o1       = (unsigned short*)(ws + 10802112);  // overlays bin

    int nblk   = (E + EB - 1) / EB;             // 3125 bin blocks
    int ncnt   = NRANGE * nblk;                 // 100000 counts
    int nb_c   = (ncnt + 255) / 256;            // 391
    int nb_n   = (n + 255) / 256;               // 391
    int nb_g32 = (n * 32 + 255) / 256;          // 12500 gather blocks
    int nb_g   = (n + GROWS - 1) / GROWS;       // 782 gemm blocks

    // 1) bin counts + bases
    k_bincount<<<nblk, 256, 0, stream>>>(dst, bktcnt, E, nblk);
    k_scan_block<<<nb_c, 256, 0, stream>>>(bktcnt, bktcnt, bsum2, ncnt);
    k_scan_tops<<<1, 512, 0, stream>>>(bsum2, bktcnt, nb_c, ncnt);
    // 2) bin edges (one int2 scatter per edge)
    k_binfill<<<nblk, 256, 0, stream>>>(src, dst, ew, bktcnt, bsum2, bin, E, nblk);
    // 3) packed hist -> dinv+rowptr -> exact 4B CSR with baked nrm
    k_hist2<<<NRANGE * NS2, 256, 0, stream>>>(bin, bktcnt, bsum2, partials, E, nblk);
    k_sumscan<<<nb_n, 256, 0, stream>>>(partials, rowptr, bsum, dinv, n);
    k_scan_tops<<<1, 512, 0, stream>>>(bsum, rowptr, nb_n, n);
    k_slicecur<<<nb_n, 256, 0, stream>>>(partials, rowptr, bsum, n);
    k_fill3<<<NRANGE * NS2, 256, 0, stream>>>(bin, bktcnt, bsum2, partials,
                                              dinv, csr, E, nblk);
    // 4) GCN pipeline (bf16 h/o1)
    k_gemm1<<<nb_g, 256, 0, stream>>>(x, w1, h, n);
    k_gather_relu<<<nb_g32, 256, 0, stream>>>(h, dinv, rowptr, bsum, csr, b1, o1, n);
    k_gather_out<<<nb_g32, 256, 0, stream>>>(o1, dinv, rowptr, bsum, csr, w2, b2, out, n);
}

// Round 26
// 248.699 us; speedup vs baseline: 1.0408x; 1.0408x over previous
//
#include <hip/hip_runtime.h>

// GCN 2-layer. Round-25 post-mortem: 32-lane gather split regressed (+11us,
// per-node overhead quadrupled while serial loop only halved) -> REVERTED
// to the 247us-measured 16-lane config. New (orthogonal): EB 1024->2048
// halves bincount/binfill grids and the bktcnt scan length.

#define NF 512
#define NH 16
#define NRANGE 32
#define NS2 32
#define RS 3125           // nodes per range = 100000/32
#define EB 2048           // edges per bin block (8/thread)
#define GROWS 128         // gemm rows per block
#define GK 16             // gemm k-chunk (double-buffered)
#define XST 20            // xs row stride in floats (80B: aligned + spread)

__device__ __forceinline__ unsigned short f2bf(float f) {
    unsigned u = __float_as_uint(f);
    return (unsigned short)((u + 0x7fff + ((u >> 16) & 1)) >> 16);   // RNE
}
__device__ __forceinline__ float bf2f(unsigned b) {
    return __uint_as_float(b << 16);
}

__global__ __launch_bounds__(256) void k_bincount(const int* __restrict__ dst,
                                                  int* __restrict__ bktcnt,
                                                  int E, int nblk) {
    __shared__ int cnt[NRANGE];
    if (threadIdx.x < NRANGE) cnt[threadIdx.x] = 0;
    __syncthreads();
    int b0 = blockIdx.x * EB;
#pragma unroll
    for (int j = 0; j < EB / 256; ++j) {
        int e = b0 + j * 256 + threadIdx.x;
        if (e < E) atomicAdd(&cnt[dst[e] / RS], 1);
    }
    __syncthreads();
    if (threadIdx.x < NRANGE)
        bktcnt[threadIdx.x * nblk + blockIdx.x] = cnt[threadIdx.x];
}

// exclusive scan (verified rounds 6-25); safe with out==in
__global__ __launch_bounds__(256) void k_scan_block(const int* __restrict__ in,
                                                    int* __restrict__ outp,
                                                    int* __restrict__ bsum, int n) {
    __shared__ int sh[256];
    int t = threadIdx.x, g = blockIdx.x * 256 + t;
    int v = (g < n) ? in[g] : 0;
    sh[t] = v; __syncthreads();
    for (int off = 1; off < 256; off <<= 1) {
        int a = (t >= off) ? sh[t - off] : 0;
        __syncthreads();
        sh[t] += a;
        __syncthreads();
    }
    if (g < n) outp[g] = sh[t] - v;
    if (t == 255) bsum[blockIdx.x] = sh[255];
}

// fused: per-node degree+weight reduction (packed), dinv write, block scan
__global__ __launch_bounds__(256) void k_sumscan(const unsigned* __restrict__ partials,
                                                 int* __restrict__ rowptr,
                                                 int* __restrict__ bsum,
                                                 float* __restrict__ dinv, int n) {
    __shared__ int sh[256];
    int t = threadIdx.x, g = blockIdx.x * 256 + t;
    int v = 0;
    if (g < n) {
        int r = g / RS, b = g - r * RS;
        const unsigned* p = partials + (size_t)(r * NS2) * RS + b;
        unsigned wq = 0;
#pragma unroll
        for (int s = 0; s < NS2; ++s) {
            unsigned pk = p[s * RS];
            v += (int)(pk >> 25);
            wq += pk & 0x1ffffffu;
        }
        dinv[g] = rsqrtf(1.0f + (float)wq * (1.0f / 1024.0f));
    }
    sh[t] = v; __syncthreads();
    for (int off = 1; off < 256; off <<= 1) {
        int a = (t >= off) ? sh[t - off] : 0;
        __syncthreads();
        sh[t] += a;
        __syncthreads();
    }
    if (g < n) rowptr[g] = sh[t] - v;     // block-local; bsum added by consumers
    if (t == 255) bsum[blockIdx.x] = sh[255];
}

__global__ __launch_bounds__(512) void k_scan_tops(int* __restrict__ bsum,
                                                   int* __restrict__ outp,
                                                   int nb, int n) {
    __shared__ int sh[512];
    int t = threadIdx.x;
    int v = (t < nb) ? bsum[t] : 0;
    sh[t] = v; __syncthreads();
    for (int off = 1; off < 512; off <<= 1) {
        int a = (t >= off) ? sh[t - off] : 0;
        __syncthreads();
        sh[t] += a;
        __syncthreads();
    }
    if (t < nb) bsum[t] = sh[t] - v;
    if (t == 511) outp[n] = sh[511];      // absolute total (E)
}

// write each edge once into its bucket; bsum2 offset applied inline
__global__ __launch_bounds__(256) void k_binfill(const int* __restrict__ src,
                                                 const int* __restrict__ dst,
                                                 const float* __restrict__ ew,
                                                 const int* __restrict__ bktcnt,
                                                 const int* __restrict__ bsum2,
                                                 int2* __restrict__ bin,
                                                 int E, int nblk) {
    __shared__ int base[NRANGE];
    if (threadIdx.x < NRANGE) {
        int idx = threadIdx.x * nblk + blockIdx.x;
        base[threadIdx.x] = bktcnt[idx] + bsum2[idx >> 8];
    }
    __syncthreads();
    int b0 = blockIdx.x * EB;
#pragma unroll
    for (int j = 0; j < EB / 256; ++j) {
        int e = b0 + j * 256 + threadIdx.x;
        if (e < E) {
            int d = dst[e];
            int r = d / RS;
            int pos = atomicAdd(&base[r], 1);          // LDS only
            bin[pos] = make_int2((src[e] << 12) | (d - r * RS),
                                 __float_as_int(ew[e]));
        }
    }
}

__device__ __forceinline__ int bkt_start(const int* bktcnt, const int* bsum2,
                                         int r, int nblk, int E) {
    if (r >= NRANGE) return E;
    int idx = r * nblk;
    return bktcnt[idx] + bsum2[idx >> 8];
}

// per-(range, slice) packed LDS histogram: (count<<25) | sum(round(ew*1024))
__global__ __launch_bounds__(256) void k_hist2(const int2* __restrict__ bin,
                                               const int* __restrict__ bktcnt,
                                               const int* __restrict__ bsum2,
                                               unsigned* __restrict__ partials,
                                               int E, int nblk) {
    __shared__ unsigned hist[RS];
    int r = blockIdx.x >> 5, s = blockIdx.x & (NS2 - 1);
    for (int t = threadIdx.x; t < RS; t += 256) hist[t] = 0;
    __syncthreads();
    int b0 = bkt_start(bktcnt, bsum2, r, nblk, E);
    int b1 = bkt_start(bktcnt, bsum2, r + 1, nblk, E);
    int len = b1 - b0, ss = (len + NS2 - 1) / NS2;
    int cs = b0 + s * ss, ce = min(cs + ss, b1);
    for (int j = cs + threadIdx.x; j < ce; j += 256) {
        int2 p2 = bin[j];
        unsigned wq = (unsigned)(__int_as_float(p2.y) * 1024.0f + 0.5f);
        atomicAdd(&hist[p2.x & 4095], (1u << 25) | wq);
    }
    __syncthreads();
    unsigned* pp = partials + (size_t)(r * NS2 + s) * RS;
    for (int t = threadIdx.x; t < RS; t += 256) pp[t] = hist[t];
}

// per-slice packed counts -> exact ABSOLUTE slot starts (bsum folded in)
__global__ __launch_bounds__(256) void k_slicecur(unsigned* __restrict__ partials,
                                                  const int* __restrict__ rowptr,
                                                  const int* __restrict__ bsum, int n) {
    int d = blockIdx.x * 256 + threadIdx.x;
    if (d >= n) return;
    int r = d / RS, b = d - r * RS;
    unsigned* p = partials + (size_t)(r * NS2) * RS + b;
    int run = rowptr[d] + bsum[d >> 8];
#pragma unroll
    for (int s = 0; s < NS2; ++s) {
        int c = (int)(p[s * RS] >> 25);
        p[s * RS] = (unsigned)run;
        run += c;
    }
}

// place edges: csr = (src<<15) | fixed15(dinv[s]*ew*dinv[d])
__global__ __launch_bounds__(256) void k_fill3(const int2* __restrict__ bin,
                                               const int* __restrict__ bktcnt,
                                               const int* __restrict__ bsum2,
                                               const unsigned* __restrict__ partials,
                                               const float* __restrict__ dinv,
                                               unsigned* __restrict__ csr,
                                               int E, int nblk) {
    __shared__ int cur[RS];
    __shared__ float dv[RS];
    int r = blockIdx.x >> 5, s = blockIdx.x & (NS2 - 1);
    const unsigned* cp = partials + (size_t)(r * NS2 + s) * RS;
    for (int t = threadIdx.x; t < RS; t += 256) {
        cur[t] = (int)cp[t];
        dv[t] = dinv[r * RS + t];
    }
    __syncthreads();
    int b0 = bkt_start(bktcnt, bsum2, r, nblk, E);
    int b1 = bkt_start(bktcnt, bsum2, r + 1, nblk, E);
    int len = b1 - b0, ss = (len + NS2 - 1) / NS2;
    int cs = b0 + s * ss, ce = min(cs + ss, b1);
    for (int j = cs + threadIdx.x; j < ce; j += 256) {
        int2 p2 = bin[j];
        int dl = p2.x & 4095;
        int sn = p2.x >> 12;
        float nrm = dinv[sn] * __int_as_float(p2.y) * dv[dl];
        unsigned w15 = (unsigned)(nrm * 32767.0f + 0.5f);
        int pos = atomicAdd(&cur[dl], 1);             // LDS only
        csr[pos] = ((unsigned)sn << 15) | w15;
    }
}

// h = x @ W1: dbuf fp32 xs (XST=20) + bf16 W1 (16KB). 36KB -> 4 blocks/CU.
__global__ __launch_bounds__(256) void k_gemm1(const float* __restrict__ x,
                                               const float* __restrict__ w1,
                                               unsigned short* __restrict__ h, int n) {
    __shared__ unsigned wtb[NF * NH / 2];  // 16KB bf16 pairs [k4][f][kk/2]
    __shared__ float xs[2][GROWS * XST];   // 2 x 10KB
    for (int idx = threadIdx.x; idx < NF * NH / 2; idx += 256) {
        int k4 = idx >> 5, rem = idx & 31;
        int f = rem >> 1, kk = (rem & 1) * 2;
        float v0 = w1[(k4 * 4 + kk) * NH + f];
        float v1 = w1[(k4 * 4 + kk + 1) * NH + f];
        wtb[idx] = (unsigned)f2bf(v0) | ((unsigned)f2bf(v1) << 16);
    }
    int rq = threadIdx.x >> 2;             // 0..63
    int fq = threadIdx.x & 3;              // 0..3
    int base = blockIdx.x * GROWS;
    float4 stage[2];
#define LOAD_CHUNK(kc)                                                        \
    _Pragma("unroll")                                                         \
    for (int li = 0; li < 2; ++li) {                                          \
        int idx = li * 256 + threadIdx.x;                                     \
        int row = idx >> 2, c4 = idx & 3;                                     \
        int rg = base + row; if (rg > n - 1) rg = n - 1;                      \
        stage[li] = *(const float4*)(x + (size_t)rg * NF + (kc) * GK + c4 * 4);\
    }
#define WRITE_CHUNK(b)                                                        \
    _Pragma("unroll")                                                         \
    for (int li = 0; li < 2; ++li) {                                          \
        int idx = li * 256 + threadIdx.x;                                     \
        int row = idx >> 2, c4 = idx & 3;                                     \
        float* p = &xs[b][row * XST + c4 * 4];                                \
        p[0] = stage[li].x; p[1] = stage[li].y;                               \
        p[2] = stage[li].z; p[3] = stage[li].w;                               \
    }
    float acc[2][4] = {{0.f}};
    LOAD_CHUNK(0)
    WRITE_CHUNK(0)
    __syncthreads();                       // also covers wtb
    for (int kc = 0; kc < NF / GK; ++kc) {
        if (kc + 1 < NF / GK) { LOAD_CHUNK(kc + 1) }   // in flight over compute
        int b = kc & 1;
#pragma unroll
        for (int k4c = 0; k4c < GK / 4; ++k4c) {
            int k4 = kc * (GK / 4) + k4c;
            float4 wf[4];
#pragma unroll
            for (int c = 0; c < 4; ++c) {
                uint2 u = *(const uint2*)&wtb[k4 * 32 + (fq * 4 + c) * 2];
                wf[c].x = __uint_as_float(u.x << 16);
                wf[c].y = __uint_as_float(u.x & 0xffff0000u);
                wf[c].z = __uint_as_float(u.y << 16);
                wf[c].w = __uint_as_float(u.y & 0xffff0000u);
            }
#pragma unroll
            for (int i = 0; i < 2; ++i) {
                int row = rq * 2 + i;
                float4 xv = *(const float4*)&xs[b][row * XST + k4c * 4];
#pragma unroll
                for (int c = 0; c < 4; ++c) {
                    acc[i][c] = fmaf(xv.x, wf[c].x, acc[i][c]);
                    acc[i][c] = fmaf(xv.y, wf[c].y, acc[i][c]);
                    acc[i][c] = fmaf(xv.z, wf[c].z, acc[i][c]);
                    acc[i][c] = fmaf(xv.w, wf[c].w, acc[i][c]);
                }
            }
        }
        if (kc + 1 < NF / GK) {
            __syncthreads();
            WRITE_CHUNK((kc + 1) & 1)      // vmcnt drain behind compute
            __syncthreads();
        }
    }
#pragma unroll
    for (int i = 0; i < 2; ++i) {
        int r = base + rq * 2 + i;
        if (r < n) {
            ushort4 o;
            o.x = f2bf(acc[i][0]); o.y = f2bf(acc[i][1]);
            o.z = f2bf(acc[i][2]); o.w = f2bf(acc[i][3]);
            *(ushort4*)(h + (size_t)r * NH + fq * 4) = o;
        }
    }
#undef LOAD_CHUNK
#undef WRITE_CHUNK
}

// layer-1 gather + bias/relu; 16 lanes/node = 2 edge-halves x 8 f-lanes
__global__ __launch_bounds__(256) void k_gather_relu(const unsigned short* __restrict__ in,
                                                     const float* __restrict__ dinv,
                                                     const int* __restrict__ rowptr,
                                                     const int* __restrict__ bsum,
                                                     const unsigned* __restrict__ csr,
                                                     const float* __restrict__ b1,
                                                     unsigned short* __restrict__ out, int n) {
    int tid = blockIdx.x * 256 + threadIdx.x;
    int d = tid >> 4, l = tid & 7, hf = (tid >> 3) & 1;
    if (d >= n) return;
    float di = dinv[d];
    float a0 = 0.0f, a1 = 0.0f;
    if (!hf) {
        unsigned self = *(const unsigned*)(in + (size_t)d * NH + 2 * l);
        a0 = bf2f(self & 0xffffu) * di * di;
        a1 = bf2f(self >> 16) * di * di;
    }
    int e0 = rowptr[d] + bsum[d >> 8];
    int e1 = (d + 1 < n) ? rowptr[d + 1] + bsum[(d + 1) >> 8] : rowptr[n];
#pragma unroll 2
    for (int j = e0 + hf; j < e1; j += 2) {
        unsigned e = csr[j];
        float nrm = (float)(e & 32767u) * (1.0f / 32767.0f);
        unsigned pr = *(const unsigned*)(in + (size_t)(e >> 15) * NH + 2 * l);
        a0 = fmaf(bf2f(pr & 0xffffu), nrm, a0);
        a1 = fmaf(bf2f(pr >> 16), nrm, a1);
    }
    a0 += __shfl_xor(a0, 8, 16);           // combine halves
    a1 += __shfl_xor(a1, 8, 16);
    if (!hf) {
        a0 = fmaxf(a0 + b1[2 * l], 0.0f);
        a1 = fmaxf(a1 + b1[2 * l + 1], 0.0f);
        unsigned pk = (unsigned)f2bf(a0) | ((unsigned)f2bf(a1) << 16);
        *(unsigned*)(out + (size_t)d * NH + 2 * l) = pk;
    }
}

// layer-2 gather + W2 + b2 + log_softmax; 16 lanes/node, halves combined,
// class math on lower 8 lanes (upper duplicates harmlessly).
__global__ __launch_bounds__(256) void k_gather_out(const unsigned short* __restrict__ in,
                                                    const float* __restrict__ dinv,
                                                    const int* __restrict__ rowptr,
                                                    const int* __restrict__ bsum,
                                                    const unsigned* __restrict__ csr,
                                                    const float* __restrict__ w2,
                                                    const float* __restrict__ b2,
                                                    float* __restrict__ out, int n) {
    __shared__ float w2s[NH * 40];
    __shared__ float b2s[40];
    for (int t = threadIdx.x; t < NH * 40; t += 256) w2s[t] = w2[t];
    if (threadIdx.x < 40) b2s[threadIdx.x] = b2[threadIdx.x];
    __syncthreads();
    int tid = blockIdx.x * 256 + threadIdx.x;
    int d = tid >> 4, l = tid & 7, hf = (tid >> 3) & 1;
    if (d >= n) return;
    float di = dinv[d];
    float a0 = 0.0f, a1 = 0.0f;
    if (!hf) {
        unsigned self = *(const unsigned*)(in + (size_t)d * NH + 2 * l);
        a0 = bf2f(self & 0xffffu) * di * di;
        a1 = bf2f(self >> 16) * di * di;
    }
    int e0 = rowptr[d] + bsum[d >> 8];
    int e1 = (d + 1 < n) ? rowptr[d + 1] + bsum[(d + 1) >> 8] : rowptr[n];
#pragma unroll 2
    for (int j = e0 + hf; j < e1; j += 2) {
        unsigned e = csr[j];
        float nrm = (float)(e & 32767u) * (1.0f / 32767.0f);
        unsigned pr = *(const unsigned*)(in + (size_t)(e >> 15) * NH + 2 * l);
        a0 = fmaf(bf2f(pr & 0xffffu), nrm, a0);
        a1 = fmaf(bf2f(pr >> 16), nrm, a1);
    }
    a0 += __shfl_xor(a0, 8, 16);           // both halves now hold full sums
    a1 += __shfl_xor(a1, 8, 16);
    // exchange 16 features within the 16-lane group (lane m and m+8 match)
    float v[NH];
#pragma unroll
    for (int m = 0; m < 8; ++m) {
        v[2 * m] = __shfl(a0, m, 16);
        v[2 * m + 1] = __shfl(a1, m, 16);
    }
    float z[5];
#pragma unroll
    for (int j5 = 0; j5 < 5; ++j5) {
        int c = l * 5 + j5;
        float a = b2s[c];
#pragma unroll
        for (int ff = 0; ff < NH; ++ff) a = fmaf(v[ff], w2s[ff * 40 + c], a);
        z[j5] = a;
    }
    float mx = z[0];
#pragma unroll
    for (int j5 = 1; j5 < 5; ++j5) mx = fmaxf(mx, z[j5]);
#pragma unroll
    for (int off = 4; off; off >>= 1) mx = fmaxf(mx, __shfl_xor(mx, off, 8));
    float sum = 0.0f;
#pragma unroll
    for (int j5 = 0; j5 < 5; ++j5) sum += expf(z[j5] - mx);
#pragma unroll
    for (int off = 4; off; off >>= 1) sum += __shfl_xor(sum, off, 8);
    float ls = mx + logf(sum);
    if (!hf) {
        float* op = out + (size_t)d * 40 + l * 5;
#pragma unroll
        for (int j5 = 0; j5 < 5; ++j5) op[j5] = z[j5] - ls;
    }
}

extern "C" void kernel_launch(void* const* d_in, const int* in_sizes, int n_in,
                              void* d_out, int out_size, void* d_ws, size_t ws_size,
                              hipStream_t stream) {
    const float* x  = (const float*)d_in[0];
    const int*   ei = (const int*)d_in[1];
    const float* ew = (const float*)d_in[2];
    const float* w1 = (const float*)d_in[3];
    const float* b1 = (const float*)d_in[4];
    const float* w2 = (const float*)d_in[5];
    const float* b2 = (const float*)d_in[6];
    float* out = (float*)d_out;

    int n = in_sizes[0] / NF;      // 100000 (= NRANGE*RS)
    int E = in_sizes[2];           // 3200000
    const int* src = ei;
    const int* dst = ei + E;

    float*          ws       = (float*)d_ws;
    float*          dinv     = ws;                        // n
    int*            bsum     = (int*)(ws + 200000);       // 1024
    int*            rowptr   = (int*)(ws + 201024);       // n+1
    int*            bsum2    = (int*)(ws + 301056);       // 1024
    int*            bktcnt   = (int*)(ws + 302080);       // 50016+
    unsigned*       partials = (unsigned*)(ws + 402112);  // 3.2M packed
    unsigned*       csr      = (unsigned*)(ws + 6802112); // E
    int2*           bin      = (int2*)(ws + 10002112);    // 2E, dead after fill3
    unsigned short* h        = (unsigned short*)(ws + 10002112);  // overlays bin
    unsigned short* o1       = (unsigned short*)(ws + 10802112);  // overlays bin

    int nblk   = (E + EB - 1) / EB;             // 1563 bin blocks
    int ncnt   = NRANGE * nblk;                 // 50016 counts
    int nb_c   = (ncnt + 255) / 256;            // 196
    int nb_n   = (n + 255) / 256;               // 391
    int nb_g16 = (n * 16 + 255) / 256;          // 6250 gather blocks
    int nb_g   = (n + GROWS - 1) / GROWS;       // 782 gemm blocks

    // 1) bin counts + bases
    k_bincount<<<nblk, 256, 0, stream>>>(dst, bktcnt, E, nblk);
    k_scan_block<<<nb_c, 256, 0, stream>>>(bktcnt, bktcnt, bsum2, ncnt);
    k_scan_tops<<<1, 512, 0, stream>>>(bsum2, bktcnt, nb_c, ncnt);
    // 2) bin edges (one int2 scatter per edge)
    k_binfill<<<nblk, 256, 0, stream>>>(src, dst, ew, bktcnt, bsum2, bin, E, nblk);
    // 3) packed hist -> dinv+rowptr -> exact 4B CSR with baked nrm
    k_hist2<<<NRANGE * NS2, 256, 0, stream>>>(bin, bktcnt, bsum2, partials, E, nblk);
    k_sumscan<<<nb_n, 256, 0, stream>>>(partials, rowptr, bsum, dinv, n);
    k_scan_tops<<<1, 512, 0, stream>>>(bsum, rowptr, nb_n, n);
    k_slicecur<<<nb_n, 256, 0, stream>>>(partials, rowptr, bsum, n);
    k_fill3<<<NRANGE * NS2, 256, 0, stream>>>(bin, bktcnt, bsum2, partials,
                                              dinv, csr, E, nblk);
    // 4) GCN pipeline (bf16 h/o1)
    k_gemm1<<<nb_g, 256, 0, stream>>>(x, w1, h, n);
    k_gather_relu<<<nb_g16, 256, 0, stream>>>(h, dinv, rowptr, bsum, csr, b1, o1, n);
    k_gather_out<<<nb_g16, 256, 0, stream>>>(o1, dinv, rowptr, bsum, csr, w2, b2, out, n);
}

// Round 27
// 245.613 us; speedup vs baseline: 1.0538x; 1.0126x over previous
//
#include <hip/hip_runtime.h>

// GCN 2-layer. Round-26: 248us (EB trim neutral; 16-lane gathers best).
// This round: k_slicecur DELETED -- fused into k_sumscan (keeps the 32
// packed slice counts in registers, writes block-local slice starts back
// into partials after its block scan). fill3 adds bsum inline while
// staging cursors. 11 launches, -25.6MB partials traffic.

#define NF 512
#define NH 16
#define NRANGE 32
#define NS2 32
#define RS 3125           // nodes per range = 100000/32
#define EB 2048           // edges per bin block (8/thread)
#define GROWS 128         // gemm rows per block
#define GK 16             // gemm k-chunk (double-buffered)
#define XST 20            // xs row stride in floats (80B: aligned + spread)

__device__ __forceinline__ unsigned short f2bf(float f) {
    unsigned u = __float_as_uint(f);
    return (unsigned short)((u + 0x7fff + ((u >> 16) & 1)) >> 16);   // RNE
}
__device__ __forceinline__ float bf2f(unsigned b) {
    return __uint_as_float(b << 16);
}

__global__ __launch_bounds__(256) void k_bincount(const int* __restrict__ dst,
                                                  int* __restrict__ bktcnt,
                                                  int E, int nblk) {
    __shared__ int cnt[NRANGE];
    if (threadIdx.x < NRANGE) cnt[threadIdx.x] = 0;
    __syncthreads();
    int b0 = blockIdx.x * EB;
#pragma unroll
    for (int j = 0; j < EB / 256; ++j) {
        int e = b0 + j * 256 + threadIdx.x;
        if (e < E) atomicAdd(&cnt[dst[e] / RS], 1);
    }
    __syncthreads();
    if (threadIdx.x < NRANGE)
        bktcnt[threadIdx.x * nblk + blockIdx.x] = cnt[threadIdx.x];
}

// exclusive scan (verified rounds 6-26); safe with out==in
__global__ __launch_bounds__(256) void k_scan_block(const int* __restrict__ in,
                                                    int* __restrict__ outp,
                                                    int* __restrict__ bsum, int n) {
    __shared__ int sh[256];
    int t = threadIdx.x, g = blockIdx.x * 256 + t;
    int v = (g < n) ? in[g] : 0;
    sh[t] = v; __syncthreads();
    for (int off = 1; off < 256; off <<= 1) {
        int a = (t >= off) ? sh[t - off] : 0;
        __syncthreads();
        sh[t] += a;
        __syncthreads();
    }
    if (g < n) outp[g] = sh[t] - v;
    if (t == 255) bsum[blockIdx.x] = sh[255];
}

// fused: degree+weight reduction, dinv, block scan, AND per-slice start
// write-back (slicecur folded in; starts are block-local, bsum added later)
__global__ __launch_bounds__(256) void k_sumscan(unsigned* __restrict__ partials,
                                                 int* __restrict__ rowptr,
                                                 int* __restrict__ bsum,
                                                 float* __restrict__ dinv, int n) {
    __shared__ int sh[256];
    int t = threadIdx.x, g = blockIdx.x * 256 + t;
    unsigned pk[NS2];
    unsigned* p = 0;
    int v = 0;
    if (g < n) {
        int r = g / RS, b = g - r * RS;
        p = partials + (size_t)(r * NS2) * RS + b;
        unsigned wq = 0;
#pragma unroll
        for (int s = 0; s < NS2; ++s) {
            pk[s] = p[s * RS];
            v += (int)(pk[s] >> 25);
            wq += pk[s] & 0x1ffffffu;
        }
        dinv[g] = rsqrtf(1.0f + (float)wq * (1.0f / 1024.0f));
    }
    sh[t] = v; __syncthreads();
    for (int off = 1; off < 256; off <<= 1) {
        int a = (t >= off) ? sh[t - off] : 0;
        __syncthreads();
        sh[t] += a;
        __syncthreads();
    }
    if (g < n) {
        int lo = sh[t] - v;                 // block-local exclusive start
        rowptr[g] = lo;
        int run = lo;
#pragma unroll
        for (int s = 0; s < NS2; ++s) {
            p[s * RS] = (unsigned)run;      // slice start (block-local)
            run += (int)(pk[s] >> 25);
        }
    }
    if (t == 255) bsum[blockIdx.x] = sh[255];
}

__global__ __launch_bounds__(512) void k_scan_tops(int* __restrict__ bsum,
                                                   int* __restrict__ outp,
                                                   int nb, int n) {
    __shared__ int sh[512];
    int t = threadIdx.x;
    int v = (t < nb) ? bsum[t] : 0;
    sh[t] = v; __syncthreads();
    for (int off = 1; off < 512; off <<= 1) {
        int a = (t >= off) ? sh[t - off] : 0;
        __syncthreads();
        sh[t] += a;
        __syncthreads();
    }
    if (t < nb) bsum[t] = sh[t] - v;
    if (t == 511) outp[n] = sh[511];      // absolute total (E)
}

// write each edge once into its bucket; bsum2 offset applied inline
__global__ __launch_bounds__(256) void k_binfill(const int* __restrict__ src,
                                                 const int* __restrict__ dst,
                                                 const float* __restrict__ ew,
                                                 const int* __restrict__ bktcnt,
                                                 const int* __restrict__ bsum2,
                                                 int2* __restrict__ bin,
                                                 int E, int nblk) {
    __shared__ int base[NRANGE];
    if (threadIdx.x < NRANGE) {
        int idx = threadIdx.x * nblk + blockIdx.x;
        base[threadIdx.x] = bktcnt[idx] + bsum2[idx >> 8];
    }
    __syncthreads();
    int b0 = blockIdx.x * EB;
#pragma unroll
    for (int j = 0; j < EB / 256; ++j) {
        int e = b0 + j * 256 + threadIdx.x;
        if (e < E) {
            int d = dst[e];
            int r = d / RS;
            int pos = atomicAdd(&base[r], 1);          // LDS only
            bin[pos] = make_int2((src[e] << 12) | (d - r * RS),
                                 __float_as_int(ew[e]));
        }
    }
}

__device__ __forceinline__ int bkt_start(const int* bktcnt, const int* bsum2,
                                         int r, int nblk, int E) {
    if (r >= NRANGE) return E;
    int idx = r * nblk;
    return bktcnt[idx] + bsum2[idx >> 8];
}

// per-(range, slice) packed LDS histogram: (count<<25) | sum(round(ew*1024))
__global__ __launch_bounds__(256) void k_hist2(const int2* __restrict__ bin,
                                               const int* __restrict__ bktcnt,
                                               const int* __restrict__ bsum2,
                                               unsigned* __restrict__ partials,
                                               int E, int nblk) {
    __shared__ unsigned hist[RS];
    int r = blockIdx.x >> 5, s = blockIdx.x & (NS2 - 1);
    for (int t = threadIdx.x; t < RS; t += 256) hist[t] = 0;
    __syncthreads();
    int b0 = bkt_start(bktcnt, bsum2, r, nblk, E);
    int b1 = bkt_start(bktcnt, bsum2, r + 1, nblk, E);
    int len = b1 - b0, ss = (len + NS2 - 1) / NS2;
    int cs = b0 + s * ss, ce = min(cs + ss, b1);
    for (int j = cs + threadIdx.x; j < ce; j += 256) {
        int2 p2 = bin[j];
        unsigned wq = (unsigned)(__int_as_float(p2.y) * 1024.0f + 0.5f);
        atomicAdd(&hist[p2.x & 4095], (1u << 25) | wq);
    }
    __syncthreads();
    unsigned* pp = partials + (size_t)(r * NS2 + s) * RS;
    for (int t = threadIdx.x; t < RS; t += 256) pp[t] = hist[t];
}

// place edges: csr = (src<<15) | fixed15(dinv[s]*ew*dinv[d]).
// cursor staging adds bsum inline (slice starts are block-local).
__global__ __launch_bounds__(256) void k_fill3(const int2* __restrict__ bin,
                                               const int* __restrict__ bktcnt,
                                               const int* __restrict__ bsum2,
                                               const unsigned* __restrict__ partials,
                                               const int* __restrict__ bsum,
                                               const float* __restrict__ dinv,
                                               unsigned* __restrict__ csr,
                                               int E, int nblk) {
    __shared__ int cur[RS];
    __shared__ float dv[RS];
    int r = blockIdx.x >> 5, s = blockIdx.x & (NS2 - 1);
    const unsigned* cp = partials + (size_t)(r * NS2 + s) * RS;
    for (int t = threadIdx.x; t < RS; t += 256) {
        int g = r * RS + t;
        cur[t] = (int)cp[t] + bsum[g >> 8];
        dv[t] = dinv[g];
    }
    __syncthreads();
    int b0 = bkt_start(bktcnt, bsum2, r, nblk, E);
    int b1 = bkt_start(bktcnt, bsum2, r + 1, nblk, E);
    int len = b1 - b0, ss = (len + NS2 - 1) / NS2;
    int cs = b0 + s * ss, ce = min(cs + ss, b1);
    for (int j = cs + threadIdx.x; j < ce; j += 256) {
        int2 p2 = bin[j];
        int dl = p2.x & 4095;
        int sn = p2.x >> 12;
        float nrm = dinv[sn] * __int_as_float(p2.y) * dv[dl];
        unsigned w15 = (unsigned)(nrm * 32767.0f + 0.5f);
        int pos = atomicAdd(&cur[dl], 1);             // LDS only
        csr[pos] = ((unsigned)sn << 15) | w15;
    }
}

// h = x @ W1: dbuf fp32 xs (XST=20) + bf16 W1 (16KB). 36KB -> 4 blocks/CU.
__global__ __launch_bounds__(256) void k_gemm1(const float* __restrict__ x,
                                               const float* __restrict__ w1,
                                               unsigned short* __restrict__ h, int n) {
    __shared__ unsigned wtb[NF * NH / 2];  // 16KB bf16 pairs [k4][f][kk/2]
    __shared__ float xs[2][GROWS * XST];   // 2 x 10KB
    for (int idx = threadIdx.x; idx < NF * NH / 2; idx += 256) {
        int k4 = idx >> 5, rem = idx & 31;
        int f = rem >> 1, kk = (rem & 1) * 2;
        float v0 = w1[(k4 * 4 + kk) * NH + f];
        float v1 = w1[(k4 * 4 + kk + 1) * NH + f];
        wtb[idx] = (unsigned)f2bf(v0) | ((unsigned)f2bf(v1) << 16);
    }
    int rq = threadIdx.x >> 2;             // 0..63
    int fq = threadIdx.x & 3;              // 0..3
    int base = blockIdx.x * GROWS;
    float4 stage[2];
#define LOAD_CHUNK(kc)                                                        \
    _Pragma("unroll")                                                         \
    for (int li = 0; li < 2; ++li) {                                          \
        int idx = li * 256 + threadIdx.x;                                     \
        int row = idx >> 2, c4 = idx & 3;                                     \
        int rg = base + row; if (rg > n - 1) rg = n - 1;                      \
        stage[li] = *(const float4*)(x + (size_t)rg * NF + (kc) * GK + c4 * 4);\
    }
#define WRITE_CHUNK(b)                                                        \
    _Pragma("unroll")                                                         \
    for (int li = 0; li < 2; ++li) {                                          \
        int idx = li * 256 + threadIdx.x;                                     \
        int row = idx >> 2, c4 = idx & 3;                                     \
        float* p = &xs[b][row * XST + c4 * 4];                                \
        p[0] = stage[li].x; p[1] = stage[li].y;                               \
        p[2] = stage[li].z; p[3] = stage[li].w;                               \
    }
    float acc[2][4] = {{0.f}};
    LOAD_CHUNK(0)
    WRITE_CHUNK(0)
    __syncthreads();                       // also covers wtb
    for (int kc = 0; kc < NF / GK; ++kc) {
        if (kc + 1 < NF / GK) { LOAD_CHUNK(kc + 1) }   // in flight over compute
        int b = kc & 1;
#pragma unroll
        for (int k4c = 0; k4c < GK / 4; ++k4c) {
            int k4 = kc * (GK / 4) + k4c;
            float4 wf[4];
#pragma unroll
            for (int c = 0; c < 4; ++c) {
                uint2 u = *(const uint2*)&wtb[k4 * 32 + (fq * 4 + c) * 2];
                wf[c].x = __uint_as_float(u.x << 16);
                wf[c].y = __uint_as_float(u.x & 0xffff0000u);
                wf[c].z = __uint_as_float(u.y << 16);
                wf[c].w = __uint_as_float(u.y & 0xffff0000u);
            }
#pragma unroll
            for (int i = 0; i < 2; ++i) {
                int row = rq * 2 + i;
                float4 xv = *(const float4*)&xs[b][row * XST + k4c * 4];
#pragma unroll
                for (int c = 0; c < 4; ++c) {
                    acc[i][c] = fmaf(xv.x, wf[c].x, acc[i][c]);
                    acc[i][c] = fmaf(xv.y, wf[c].y, acc[i][c]);
                    acc[i][c] = fmaf(xv.z, wf[c].z, acc[i][c]);
                    acc[i][c] = fmaf(xv.w, wf[c].w, acc[i][c]);
                }
            }
        }
        if (kc + 1 < NF / GK) {
            __syncthreads();
            WRITE_CHUNK((kc + 1) & 1)      // vmcnt drain behind compute
            __syncthreads();
        }
    }
#pragma unroll
    for (int i = 0; i < 2; ++i) {
        int r = base + rq * 2 + i;
        if (r < n) {
            ushort4 o;
            o.x = f2bf(acc[i][0]); o.y = f2bf(acc[i][1]);
            o.z = f2bf(acc[i][2]); o.w = f2bf(acc[i][3]);
            *(ushort4*)(h + (size_t)r * NH + fq * 4) = o;
        }
    }
#undef LOAD_CHUNK
#undef WRITE_CHUNK
}

// layer-1 gather + bias/relu; 16 lanes/node = 2 edge-halves x 8 f-lanes
__global__ __launch_bounds__(256) void k_gather_relu(const unsigned short* __restrict__ in,
                                                     const float* __restrict__ dinv,
                                                     const int* __restrict__ rowptr,
                                                     const int* __restrict__ bsum,
                                                     const unsigned* __restrict__ csr,
                                                     const float* __restrict__ b1,
                                                     unsigned short* __restrict__ out, int n) {
    int tid = blockIdx.x * 256 + threadIdx.x;
    int d = tid >> 4, l = tid & 7, hf = (tid >> 3) & 1;
    if (d >= n) return;
    float di = dinv[d];
    float a0 = 0.0f, a1 = 0.0f;
    if (!hf) {
        unsigned self = *(const unsigned*)(in + (size_t)d * NH + 2 * l);
        a0 = bf2f(self & 0xffffu) * di * di;
        a1 = bf2f(self >> 16) * di * di;
    }
    int e0 = rowptr[d] + bsum[d >> 8];
    int e1 = (d + 1 < n) ? rowptr[d + 1] + bsum[(d + 1) >> 8] : rowptr[n];
#pragma unroll 2
    for (int j = e0 + hf; j < e1; j += 2) {
        unsigned e = csr[j];
        float nrm = (float)(e & 32767u) * (1.0f / 32767.0f);
        unsigned pr = *(const unsigned*)(in + (size_t)(e >> 15) * NH + 2 * l);
        a0 = fmaf(bf2f(pr & 0xffffu), nrm, a0);
        a1 = fmaf(bf2f(pr >> 16), nrm, a1);
    }
    a0 += __shfl_xor(a0, 8, 16);           // combine halves
    a1 += __shfl_xor(a1, 8, 16);
    if (!hf) {
        a0 = fmaxf(a0 + b1[2 * l], 0.0f);
        a1 = fmaxf(a1 + b1[2 * l + 1], 0.0f);
        unsigned pk = (unsigned)f2bf(a0) | ((unsigned)f2bf(a1) << 16);
        *(unsigned*)(out + (size_t)d * NH + 2 * l) = pk;
    }
}

// layer-2 gather + W2 + b2 + log_softmax; 16 lanes/node, halves combined,
// class math on lower 8 lanes (upper duplicates harmlessly).
__global__ __launch_bounds__(256) void k_gather_out(const unsigned short* __restrict__ in,
                                                    const float* __restrict__ dinv,
                                                    const int* __restrict__ rowptr,
                                                    const int* __restrict__ bsum,
                                                    const unsigned* __restrict__ csr,
                                                    const float* __restrict__ w2,
                                                    const float* __restrict__ b2,
                                                    float* __restrict__ out, int n) {
    __shared__ float w2s[NH * 40];
    __shared__ float b2s[40];
    for (int t = threadIdx.x; t < NH * 40; t += 256) w2s[t] = w2[t];
    if (threadIdx.x < 40) b2s[threadIdx.x] = b2[threadIdx.x];
    __syncthreads();
    int tid = blockIdx.x * 256 + threadIdx.x;
    int d = tid >> 4, l = tid & 7, hf = (tid >> 3) & 1;
    if (d >= n) return;
    float di = dinv[d];
    float a0 = 0.0f, a1 = 0.0f;
    if (!hf) {
        unsigned self = *(const unsigned*)(in + (size_t)d * NH + 2 * l);
        a0 = bf2f(self & 0xffffu) * di * di;
        a1 = bf2f(self >> 16) * di * di;
    }
    int e0 = rowptr[d] + bsum[d >> 8];
    int e1 = (d + 1 < n) ? rowptr[d + 1] + bsum[(d + 1) >> 8] : rowptr[n];
#pragma unroll 2
    for (int j = e0 + hf; j < e1; j += 2) {
        unsigned e = csr[j];
        float nrm = (float)(e & 32767u) * (1.0f / 32767.0f);
        unsigned pr = *(const unsigned*)(in + (size_t)(e >> 15) * NH + 2 * l);
        a0 = fmaf(bf2f(pr & 0xffffu), nrm, a0);
        a1 = fmaf(bf2f(pr >> 16), nrm, a1);
    }
    a0 += __shfl_xor(a0, 8, 16);           // both halves now hold full sums
    a1 += __shfl_xor(a1, 8, 16);
    // exchange 16 features within the 16-lane group (lane m and m+8 match)
    float v[NH];
#pragma unroll
    for (int m = 0; m < 8; ++m) {
        v[2 * m] = __shfl(a0, m, 16);
        v[2 * m + 1] = __shfl(a1, m, 16);
    }
    float z[5];
#pragma unroll
    for (int j5 = 0; j5 < 5; ++j5) {
        int c = l * 5 + j5;
        float a = b2s[c];
#pragma unroll
        for (int ff = 0; ff < NH; ++ff) a = fmaf(v[ff], w2s[ff * 40 + c], a);
        z[j5] = a;
    }
    float mx = z[0];
#pragma unroll
    for (int j5 = 1; j5 < 5; ++j5) mx = fmaxf(mx, z[j5]);
#pragma unroll
    for (int off = 4; off; off >>= 1) mx = fmaxf(mx, __shfl_xor(mx, off, 8));
    float sum = 0.0f;
#pragma unroll
    for (int j5 = 0; j5 < 5; ++j5) sum += expf(z[j5] - mx);
#pragma unroll
    for (int off = 4; off; off >>= 1) sum += __shfl_xor(sum, off, 8);
    float ls = mx + logf(sum);
    if (!hf) {
        float* op = out + (size_t)d * 40 + l * 5;
#pragma unroll
        for (int j5 = 0; j5 < 5; ++j5) op[j5] = z[j5] - ls;
    }
}

extern "C" void kernel_launch(void* const* d_in, const int* in_sizes, int n_in,
                              void* d_out, int out_size, void* d_ws, size_t ws_size,
                              hipStream_t stream) {
    const float* x  = (const float*)d_in[0];
    const int*   ei = (const int*)d_in[1];
    const float* ew = (const float*)d_in[2];
    const float* w1 = (const float*)d_in[3];
    const float* b1 = (const float*)d_in[4];
    const float* w2 = (const float*)d_in[5];
    const float* b2 = (const float*)d_in[6];
    float* out = (float*)d_out;

    int n = in_sizes[0] / NF;      // 100000 (= NRANGE*RS)
    int E = in_sizes[2];           // 3200000
    const int* src = ei;
    const int* dst = ei + E;

    float*          ws       = (float*)d_ws;
    float*          dinv     = ws;                        // n
    int*            bsum     = (int*)(ws + 200000);       // 1024
    int*            rowptr   = (int*)(ws + 201024);       // n+1
    int*            bsum2    = (int*)(ws + 301056);       // 1024
    int*            bktcnt   = (int*)(ws + 302080);       // 50016+
    unsigned*       partials = (unsigned*)(ws + 402112);  // 3.2M packed
    unsigned*       csr      = (unsigned*)(ws + 6802112); // E
    int2*           bin      = (int2*)(ws + 10002112);    // 2E, dead after fill3
    unsigned short* h        = (unsigned short*)(ws + 10002112);  // overlays bin
    unsigned short* o1       = (unsigned short*)(ws + 10802112);  // overlays bin

    int nblk   = (E + EB - 1) / EB;             // 1563 bin blocks
    int ncnt   = NRANGE * nblk;                 // 50016 counts
    int nb_c   = (ncnt + 255) / 256;            // 196
    int nb_n   = (n + 255) / 256;               // 391
    int nb_g16 = (n * 16 + 255) / 256;          // 6250 gather blocks
    int nb_g   = (n + GROWS - 1) / GROWS;       // 782 gemm blocks

    // 1) bin counts + bases
    k_bincount<<<nblk, 256, 0, stream>>>(dst, bktcnt, E, nblk);
    k_scan_block<<<nb_c, 256, 0, stream>>>(bktcnt, bktcnt, bsum2, ncnt);
    k_scan_tops<<<1, 512, 0, stream>>>(bsum2, bktcnt, nb_c, ncnt);
    // 2) bin edges (one int2 scatter per edge)
    k_binfill<<<nblk, 256, 0, stream>>>(src, dst, ew, bktcnt, bsum2, bin, E, nblk);
    // 3) packed hist -> dinv+rowptr+slice-starts (fused) -> exact 4B CSR
    k_hist2<<<NRANGE * NS2, 256, 0, stream>>>(bin, bktcnt, bsum2, partials, E, nblk);
    k_sumscan<<<nb_n, 256, 0, stream>>>(partials, rowptr, bsum, dinv, n);
    k_scan_tops<<<1, 512, 0, stream>>>(bsum, rowptr, nb_n, n);
    k_fill3<<<NRANGE * NS2, 256, 0, stream>>>(bin, bktcnt, bsum2, partials,
                                              bsum, dinv, csr, E, nblk);
    // 4) GCN pipeline (bf16 h/o1)
    k_gemm1<<<nb_g, 256, 0, stream>>>(x, w1, h, n);
    k_gather_relu<<<nb_g16, 256, 0, stream>>>(h, dinv, rowptr, bsum, csr, b1, o1, n);
    k_gather_out<<<nb_g16, 256, 0, stream>>>(o1, dinv, rowptr, bsum, csr, w2, b2, out, n);
}